// Round 6
// baseline (506.713 us; speedup 1.0000x reference)
//
#include <hip/hip_runtime.h>
#include <hip/hip_bf16.h>
#include <math.h>

#define CB 4
#define CS 2048
#define CC 1024
#define CH 16
#define CD 64
#define CBS (CB*CS)   // 8192 tokens

typedef unsigned short u16;
typedef __bf16 bf16x8 __attribute__((ext_vector_type(8)));
typedef float f32x4 __attribute__((ext_vector_type(4)));
typedef float f32x16 __attribute__((ext_vector_type(16)));
typedef unsigned short u16x4 __attribute__((ext_vector_type(4)));
typedef unsigned short u16x8 __attribute__((ext_vector_type(8)));

__device__ __forceinline__ u16 f2bf(float f){
  union { float f; unsigned u; } v; v.f = f;
  unsigned r = v.u + 0x7FFFu + ((v.u >> 16) & 1u);   // RNE
  return (u16)(r >> 16);
}
__device__ __forceinline__ unsigned pack2bf(float a, float b){
  __hip_bfloat162 h = __float22bfloat162_rn(make_float2(a, b));
  union { __hip_bfloat162 h; unsigned u; } c; c.h = h; return c.u;
}
__device__ __forceinline__ f32x4 mfma16(bf16x8 a, bf16x8 b, f32x4 c){
  return __builtin_amdgcn_mfma_f32_16x16x32_bf16(a, b, c, 0, 0, 0);
}
__device__ __forceinline__ f32x16 mfma32(bf16x8 a, bf16x8 b, f32x16 c){
  return __builtin_amdgcn_mfma_f32_32x32x16_bf16(a, b, c, 0, 0, 0);
}
// async global->LDS, 16B per lane. lds base must be WAVE-UNIFORM; HW scatters
// lane i to base + i*16B (m104/m108). Global ptr is per-lane.
__device__ __forceinline__ void gload16(const u16* g, u16* lds_base_uniform){
  __builtin_amdgcn_global_load_lds(
      (const __attribute__((address_space(1))) unsigned int*)g,
      (__attribute__((address_space(3))) unsigned int*)lds_base_uniform, 16, 0, 0);
}

// ---------------------------------------------------------------------------
// x fp32 -> bf16 (and zero the 4 entropy accumulators)
// ---------------------------------------------------------------------------
__global__ __launch_bounds__(256) void convert_x_kernel(
    const float* __restrict__ x, u16* __restrict__ xb, float* __restrict__ zero4){
  if (blockIdx.x == 0 && threadIdx.x < 4) zero4[threadIdx.x] = 0.0f;
  size_t i = ((size_t)blockIdx.x*256 + threadIdx.x)*8;
  float4 a = *(const float4*)(x+i);
  float4 b = *(const float4*)(x+i+4);
  u16x8 o = { f2bf(a.x),f2bf(a.y),f2bf(a.z),f2bf(a.w),
              f2bf(b.x),f2bf(b.y),f2bf(b.z),f2bf(b.w) };
  *(u16x8*)(xb+i) = o;
}

// ---------------------------------------------------------------------------
// Transpose + fp32->bf16:  w[K][N] -> wt[N][K]
// ---------------------------------------------------------------------------
template<int K, int N>
__global__ __launch_bounds__(256) void transpose_convert_kernel(
    const float* __restrict__ w, u16* __restrict__ wt){
  __shared__ u16 tile[64][65];
  const int nb = N/64;
  int tk0 = (blockIdx.x / nb) * 64;
  int tn0 = (blockIdx.x % nb) * 64;
  int t = threadIdx.x;
  for (int i = 0; i < 4; i++) {
    int r = i*16 + (t>>4);
    int c = (t&15)*4;
    float4 v = *(const float4*)(w + (size_t)(tk0+r)*N + tn0 + c);
    tile[c+0][r]=f2bf(v.x); tile[c+1][r]=f2bf(v.y);
    tile[c+2][r]=f2bf(v.z); tile[c+3][r]=f2bf(v.w);
  }
  __syncthreads();
  for (int i = 0; i < 4; i++) {
    int r = i*16 + (t>>4);
    int c = (t&15)*4;
    u16x4 o = { tile[r][c+0], tile[r][c+1], tile[r][c+2], tile[r][c+3] };
    *(u16x4*)(wt + (size_t)(tn0+r)*K + tk0 + c) = o;
  }
}

// ---------------------------------------------------------------------------
// V [B,H,S,D] -> V^T [B,H,D,S]
// ---------------------------------------------------------------------------
__global__ __launch_bounds__(256) void transpose_v_kernel(
    const u16* __restrict__ vb, u16* __restrict__ vtb){
  __shared__ u16 tile[64][72];
  int bh = blockIdx.x >> 5;
  int st = blockIdx.x & 31;
  int t = threadIdx.x;
  const u16* src = vb + (size_t)bh*CS*CD + (size_t)st*64*CD;
  int r = t>>2, c = (t&3)*16;
  *(u16x8*)&tile[r][c]   = *(const u16x8*)(src + (size_t)r*CD + c);
  *(u16x8*)&tile[r][c+8] = *(const u16x8*)(src + (size_t)r*CD + c + 8);
  __syncthreads();
  int d = t>>2, s = (t&3)*16;
  u16x8 o0, o1;
  for (int j=0;j<8;j++){ o0[j] = tile[s+j][d]; o1[j] = tile[s+8+j][d]; }
  u16* dst = vtb + (size_t)bh*CD*CS + (size_t)d*CS + st*64 + s;
  *(u16x8*)dst = o0;
  *(u16x8*)(dst+8) = o1;
}

// ---------------------------------------------------------------------------
// GEMM1: qkv = xb @ wqkvT^T, m97-style global_load_lds staging, LN epilogue.
// ---------------------------------------------------------------------------
__global__ __launch_bounds__(256, 2) void gemm_qkv_ln_kernel(
    const u16* __restrict__ xb, const u16* __restrict__ wqkvT,
    const float* __restrict__ qsc, const float* __restrict__ qbi,
    const float* __restrict__ ksc, const float* __restrict__ kbi,
    u16* __restrict__ qb, u16* __restrict__ kb, u16* __restrict__ vb){
  __shared__ u16 al[128*64];
  __shared__ u16 bl[128*64];
  int t = threadIdx.x;
  int wv = t >> 6, lane = t & 63, lo = lane & 15, q4 = lane >> 4;
  int m0 = blockIdx.x * 128;
  int n0 = blockIdx.y * 128;
  int srow = lane >> 3, scol = (lane & 7) * 8;   // 8 rows x 64 cols per gload16
  const u16* ag = xb    + (size_t)(m0 + srow)*CC + scol;
  const u16* bg = wqkvT + (size_t)(n0 + srow)*CC + scol;

  f32x4 acc[2][8];
  for (int i=0;i<2;i++) for (int j=0;j<8;j++) acc[i][j] = (f32x4){0.f,0.f,0.f,0.f};

  for (int kk = 0; kk < 16; kk++){
    int k0 = kk * 64;
    for (int i = 0; i < 4; i++){
      int inst = i*4 + wv;
      gload16(ag + (size_t)inst*8*CC + k0, al + inst*512);
      gload16(bg + (size_t)inst*8*CC + k0, bl + inst*512);
    }
    __syncthreads();
    for (int ksI = 0; ksI < 2; ksI++){
      int koff = ksI*32 + q4*8;
      bf16x8 a0 = *(const bf16x8*)&al[(wv*32      + lo)*64 + koff];
      bf16x8 a1 = *(const bf16x8*)&al[(wv*32 + 16 + lo)*64 + koff];
      for (int nt=0; nt<8; nt++){
        bf16x8 b = *(const bf16x8*)&bl[(nt*16 + lo)*64 + koff];
        acc[0][nt] = mfma16(a0, b, acc[0][nt]);
        acc[1][nt] = mfma16(a1, b, acc[1][nt]);
      }
    }
    __syncthreads();
  }

  int three = n0 >> 10;
  int h0 = (n0 & 1023) >> 6;
  const float* scp = (three == 0) ? qsc : ksc;
  const float* bip = (three == 0) ? qbi : kbi;
  float outscale = (three == 0) ? 0.125f : 1.0f;   // fold 1/sqrt(D) into q
  u16* dst = (three == 0) ? qb : (three == 1 ? kb : vb);

  for (int rt = 0; rt < 2; rt++){
    int tg = m0 + wv*32 + rt*16 + q4*4;
    for (int hf = 0; hf < 2; hf++){
      int h = h0 + hf;
      for (int r = 0; r < 4; r++){
        int token = tg + r;
        int bb = token >> 11, ss = token & (CS-1);
        size_t base = (((size_t)(bb*CH + h))*CS + ss)*CD;
        if (three < 2){
          float s1 = 0.f, s2 = 0.f;
          for (int j=0;j<4;j++){ float v = acc[rt][hf*4+j][r]; s1 += v; s2 += v*v; }
          for (int off=8; off>=1; off>>=1){
            s1 += __shfl_xor(s1, off, 16);
            s2 += __shfl_xor(s2, off, 16);
          }
          float mean = s1 * (1.f/64.f);
          float var  = s2 * (1.f/64.f) - mean*mean;
          float rstd = rsqrtf(var + 1e-5f);
          for (int j=0;j<4;j++){
            int d = j*16 + lo;
            float v = (acc[rt][hf*4+j][r] - mean) * rstd * scp[d] + bip[d];
            dst[base + d] = f2bf(v * outscale);
          }
        } else {
          for (int j=0;j<4;j++){
            int d = j*16 + lo;
            dst[base + d] = f2bf(acc[rt][hf*4+j][r]);
          }
        }
      }
    }
  }
}

// ---------------------------------------------------------------------------
// Attention: S^T = K.Q^T via 32x32x16 MFMA, 32-sk tiles (register diet for
// 3 waves/EU). No barriers, no online max (|logit| <= 8 after LN + folded
// 0.125). K register double-buffered; V loaded at top of iter (consumed
// after S-MFMA + exp). XCD swizzle keeps each head's K/V L2-resident.
// Output is HEAD-MAJOR [B,H,S,D]: contiguous 16-KB writes per block, no
// cross-XCD cache-line sharing (round-5 write-amplification fix).
// ---------------------------------------------------------------------------
__global__ __launch_bounds__(256, 3) void attention_kernel(
    const u16* __restrict__ qb, const u16* __restrict__ kb,
    const u16* __restrict__ vtb, u16* __restrict__ attnb, float* __restrict__ ent){
  __shared__ __align__(16) u16 pl[4][32][40];   // per-wave P (A-layout), stride 80B (16B-aligned)
  __shared__ __align__(16) float zl[4][32];
  int t = threadIdx.x;
  int wv = t >> 6, lane = t & 63;
  int col = lane & 31, hi = lane >> 5;
  // XCD swizzle: block n runs on XCD n%8; give each XCD 8 whole (b,h) heads.
  int n = blockIdx.x;
  int xc = n & 7, j = n >> 3;
  int bh = xc + 8*(j >> 4);
  int qt = j & 15;
  int bI = bh >> 4;
  int q0w = qt*128 + wv*32;
  const u16* qbp = qb  + (size_t)bh * CS * CD;
  const u16* kbp = kb  + (size_t)bh * CS * CD;
  const u16* vbp = vtb + (size_t)bh * CD * CS;

  // Q B-frags, held for the whole kernel
  bf16x8 qf[4];
  for (int ks=0;ks<4;ks++)
    qf[ks] = *(const bf16x8*)(qbp + (size_t)(q0w + col)*CD + ks*16 + hi*8);

  f32x16 o[2];
  for (int nt=0;nt<2;nt++) for (int i=0;i<16;i++) o[nt][i] = 0.f;
  float zacc = 0.f, tacc = 0.f;

  // K ping-pong (32 sk-rows x 64 d per buffer = 16 VGPR each)
  bf16x8 kf2[2][4];
  for (int ks=0;ks<4;ks++)
    kf2[0][ks] = *(const bf16x8*)(kbp + (size_t)col*CD + ks*16 + hi*8);

  #pragma unroll 2
  for (int it = 0; it < 64; it++){
    const int cur = it & 1, nxt = cur ^ 1;
    const int sk0 = it * 32;
    const int skn = ((it+1) & 63) * 32;   // last iter wraps to tile 0 (harmless)

    // --- V^T for CURRENT tile (first used after S-MFMA + exp) ---
    bf16x8 vf[2][2];
    for (int nt=0;nt<2;nt++)
      for (int ks=0;ks<2;ks++)
        vf[nt][ks] = *(const bf16x8*)(vbp + (size_t)(nt*32 + col)*CS + sk0 + ks*16 + hi*8);

    // --- prefetch K for tile it+1 ---
    for (int ks=0;ks<4;ks++)
      kf2[nxt][ks] = *(const bf16x8*)(kbp + (size_t)(skn + col)*CD + ks*16 + hi*8);

    // --- S^T = K . Q^T (32 sk-rows x 32 q-cols) ---
    f32x16 sf;
    for (int i=0;i<16;i++) sf[i] = 0.f;
    for (int ks=0;ks<4;ks++)
      sf = mfma32(kf2[cur][ks], qf[ks], sf);

    // --- exp + Z/T partials + pack P (C row = (reg&3)+8*(reg>>2)+4*hi) ---
    for (int g=0; g<4; g++){
      float l0 = sf[g*4+0], l1 = sf[g*4+1], l2 = sf[g*4+2], l3 = sf[g*4+3];
      float p0=__expf(l0), p1=__expf(l1), p2=__expf(l2), p3=__expf(l3);
      zacc += (p0+p1)+(p2+p3);
      tacc += (p0*l0+p1*l1)+(p2*l2+p3*l3);
      union { u16x4 v; unsigned u[2]; } pk;
      pk.u[0] = pack2bf(p0, p1);
      pk.u[1] = pack2bf(p2, p3);
      *(u16x4*)&pl[wv][col][g*8 + hi*4] = pk.v;   // sk-rows g*8+hi*4+(0..3), q=col
    }

    // --- O += P . V (P re-read in A-layout: row=q=col, k=sk-within-tile) ---
    for (int ks=0;ks<2;ks++){
      bf16x8 ap = *(const bf16x8*)&pl[wv][col][ks*16 + hi*8];
      o[0] = mfma32(ap, vf[0][ks], o[0]);
      o[1] = mfma32(ap, vf[1][ks], o[1]);
    }
  }

  // finalize: combine hi-halves of Z/T (lane col owns q-row col)
  float z2 = zacc + __shfl_xor(zacc, 32);
  float t2 = tacc + __shfl_xor(tacc, 32);
  float invz = 1.f / z2;
  if (hi == 0) zl[wv][col] = invz;

  // entropy: sum rows' (logZ - T/Z) over this wave, one atomic per wave
  float srow = __logf(z2) - t2 * invz;
  float ev = (hi == 0) ? srow : 0.f;
  for (int off=1; off<=32; off<<=1) ev += __shfl_xor(ev, off);
  if (lane == 0){
    float entscale = 1.0f / ((float)CH * (float)CS * logf((float)CS));
    atomicAdd(&ent[bI], ev * entscale);
  }

  // O write, head-major [B,H,S,D] (C: col=d-within-32, row=(reg&3)+8*(reg>>2)+4*hi)
  u16* obase = attnb + ((size_t)bh*CS + q0w)*CD;
  for (int nt=0;nt<2;nt++){
    for (int g=0;g<4;g++){
      f32x4 iz = *(const f32x4*)&zl[wv][g*8 + hi*4];
      for (int r=0;r<4;r++){
        int qrow = 8*g + 4*hi + r;
        obase[(size_t)qrow*CD + nt*32 + col] = f2bf(o[nt][g*4+r] * iz[r]);
      }
    }
  }
}

// ---------------------------------------------------------------------------
// GEMM3: out = attnH @ w_proj. attnH is head-major [B,H,S,D]; K-tile kk is
// exactly head kk, so A-loads are fully contiguous (1 KB per gload16).
// ---------------------------------------------------------------------------
__global__ __launch_bounds__(256, 2) void gemm_out_kernel(
    const u16* __restrict__ attnH, const u16* __restrict__ wprojT,
    float* __restrict__ out){
  __shared__ u16 al[128*64];
  __shared__ u16 bl[128*64];
  int t = threadIdx.x;
  int wv = t >> 6, lane = t & 63, lo = lane & 15, q4 = lane >> 4;
  int m0 = blockIdx.x * 128;
  int n0 = blockIdx.y * 128;
  int b  = m0 >> 11, s0 = m0 & (CS-1);
  int srow = lane >> 3, scol = (lane & 7) * 8;
  const u16* bg = wprojT + (size_t)(n0 + srow)*CC + scol;

  f32x4 acc[2][8];
  for (int i=0;i<2;i++) for (int j=0;j<8;j++) acc[i][j] = (f32x4){0.f,0.f,0.f,0.f};

  for (int kk = 0; kk < 16; kk++){
    const u16* abase = attnH + ((size_t)(b*CH + kk)*CS + s0 + srow)*CD + scol;
    for (int i = 0; i < 4; i++){
      int inst = i*4 + wv;
      gload16(abase + (size_t)inst*8*CD, al + inst*512);
      gload16(bg + (size_t)inst*8*CC + kk*64, bl + inst*512);
    }
    __syncthreads();
    for (int ksI = 0; ksI < 2; ksI++){
      int koff = ksI*32 + q4*8;
      bf16x8 a0 = *(const bf16x8*)&al[(wv*32      + lo)*64 + koff];
      bf16x8 a1 = *(const bf16x8*)&al[(wv*32 + 16 + lo)*64 + koff];
      for (int nt=0; nt<8; nt++){
        bf16x8 b2 = *(const bf16x8*)&bl[(nt*16 + lo)*64 + koff];
        acc[0][nt] = mfma16(a0, b2, acc[0][nt]);
        acc[1][nt] = mfma16(a1, b2, acc[1][nt]);
      }
    }
    __syncthreads();
  }

  for (int rt=0;rt<2;rt++){
    for (int r=0;r<4;r++){
      int row = m0 + wv*32 + rt*16 + q4*4 + r;
      for (int nt=0;nt<8;nt++)
        out[(size_t)row*CC + n0 + nt*16 + lo] = acc[rt][nt][r];
    }
  }
}

// ---------------------------------------------------------------------------
extern "C" void kernel_launch(void* const* d_in, const int* in_sizes, int n_in,
                              void* d_out, int out_size, void* d_ws, size_t ws_size,
                              hipStream_t stream) {
  const float* x      = (const float*)d_in[0];
  const float* w_qkv  = (const float*)d_in[1];
  const float* w_proj = (const float*)d_in[2];
  const float* q_scale= (const float*)d_in[3];
  const float* q_bias = (const float*)d_in[4];
  const float* k_scale= (const float*)d_in[5];
  const float* k_bias = (const float*)d_in[6];
  float* out = (float*)d_out;
  float* ent = out + (size_t)CBS * CC;

  // workspace: 75.5 MB total, with lifetime-based aliasing:
  //   xb slot reused as vbT; vb slot reused as attn (both [B,H,S,D]).
  u16* xb     = (u16*)d_ws;                       // [8192][1024]  (later: vbT [B,H,D,S])
  u16* wqkvT  = xb     + (size_t)CBS*CC;          // [3072][1024]
  u16* wprojT = wqkvT  + (size_t)3*CC*CC;         // [1024][1024]
  u16* qb     = wprojT + (size_t)CC*CC;           // [B,H,S,D]
  u16* kb     = qb + (size_t)CB*CH*CS*CD;
  u16* vb     = kb + (size_t)CB*CH*CS*CD;         // (later: attnH [B,H,S,D])
  u16* vbT    = xb;
  u16* attn   = vb;

  convert_x_kernel<<<dim3(CBS*CC/(256*8)), 256, 0, stream>>>(x, xb, ent);
  transpose_convert_kernel<CC, 3*CC><<<dim3((CC/64)*(3*CC/64)), 256, 0, stream>>>(w_qkv, wqkvT);
  transpose_convert_kernel<CC, CC><<<dim3((CC/64)*(CC/64)), 256, 0, stream>>>(w_proj, wprojT);
  gemm_qkv_ln_kernel<<<dim3(CBS/128, 3*CC/128), 256, 0, stream>>>(
      xb, wqkvT, q_scale, q_bias, k_scale, k_bias, qb, kb, vb);
  transpose_v_kernel<<<dim3(CB*CH*(CS/64)), 256, 0, stream>>>(vb, vbT);
  attention_kernel<<<dim3(CB*CH*(CS/128)), 256, 0, stream>>>(qb, kb, vbT, attn, ent);
  gemm_out_kernel<<<dim3(CBS/128, CC/128), 256, 0, stream>>>(attn, wprojT, out);
}

// Round 7
// 349.177 us; speedup vs baseline: 1.4512x; 1.4512x over previous
//
#include <hip/hip_runtime.h>
#include <hip/hip_bf16.h>
#include <math.h>

#define CB 4
#define CS 2048
#define CC 1024
#define CH 16
#define CD 64
#define CBS (CB*CS)   // 8192 tokens

typedef unsigned short u16;
typedef __bf16 bf16x8 __attribute__((ext_vector_type(8)));
typedef float f32x4 __attribute__((ext_vector_type(4)));
typedef float f32x16 __attribute__((ext_vector_type(16)));
typedef unsigned short u16x4 __attribute__((ext_vector_type(4)));
typedef unsigned short u16x8 __attribute__((ext_vector_type(8)));

__device__ __forceinline__ u16 f2bf(float f){
  union { float f; unsigned u; } v; v.f = f;
  unsigned r = v.u + 0x7FFFu + ((v.u >> 16) & 1u);   // RNE
  return (u16)(r >> 16);
}
__device__ __forceinline__ unsigned pack2bf(float a, float b){
  __hip_bfloat162 h = __float22bfloat162_rn(make_float2(a, b));
  union { __hip_bfloat162 h; unsigned u; } c; c.h = h; return c.u;
}
__device__ __forceinline__ f32x4 mfma16(bf16x8 a, bf16x8 b, f32x4 c){
  return __builtin_amdgcn_mfma_f32_16x16x32_bf16(a, b, c, 0, 0, 0);
}
__device__ __forceinline__ f32x16 mfma32(bf16x8 a, bf16x8 b, f32x16 c){
  return __builtin_amdgcn_mfma_f32_32x32x16_bf16(a, b, c, 0, 0, 0);
}
// async global->LDS, 16B per lane. lds base must be WAVE-UNIFORM; HW scatters
// lane i to base + i*16B (m104/m108). Global ptr is per-lane.
__device__ __forceinline__ void gload16(const u16* g, u16* lds_base_uniform){
  __builtin_amdgcn_global_load_lds(
      (const __attribute__((address_space(1))) unsigned int*)g,
      (__attribute__((address_space(3))) unsigned int*)lds_base_uniform, 16, 0, 0);
}

// ---------------------------------------------------------------------------
// x fp32 -> bf16 (and zero the 4 entropy accumulators)
// ---------------------------------------------------------------------------
__global__ __launch_bounds__(256) void convert_x_kernel(
    const float* __restrict__ x, u16* __restrict__ xb, float* __restrict__ zero4){
  if (blockIdx.x == 0 && threadIdx.x < 4) zero4[threadIdx.x] = 0.0f;
  size_t i = ((size_t)blockIdx.x*256 + threadIdx.x)*8;
  float4 a = *(const float4*)(x+i);
  float4 b = *(const float4*)(x+i+4);
  u16x8 o = { f2bf(a.x),f2bf(a.y),f2bf(a.z),f2bf(a.w),
              f2bf(b.x),f2bf(b.y),f2bf(b.z),f2bf(b.w) };
  *(u16x8*)(xb+i) = o;
}

// ---------------------------------------------------------------------------
// Transpose + fp32->bf16:  w[K][N] -> wt[N][K]
// ---------------------------------------------------------------------------
template<int K, int N>
__global__ __launch_bounds__(256) void transpose_convert_kernel(
    const float* __restrict__ w, u16* __restrict__ wt){
  __shared__ u16 tile[64][65];
  const int nb = N/64;
  int tk0 = (blockIdx.x / nb) * 64;
  int tn0 = (blockIdx.x % nb) * 64;
  int t = threadIdx.x;
  for (int i = 0; i < 4; i++) {
    int r = i*16 + (t>>4);
    int c = (t&15)*4;
    float4 v = *(const float4*)(w + (size_t)(tk0+r)*N + tn0 + c);
    tile[c+0][r]=f2bf(v.x); tile[c+1][r]=f2bf(v.y);
    tile[c+2][r]=f2bf(v.z); tile[c+3][r]=f2bf(v.w);
  }
  __syncthreads();
  for (int i = 0; i < 4; i++) {
    int r = i*16 + (t>>4);
    int c = (t&15)*4;
    u16x4 o = { tile[r][c+0], tile[r][c+1], tile[r][c+2], tile[r][c+3] };
    *(u16x4*)(wt + (size_t)(tn0+r)*K + tk0 + c) = o;
  }
}

// ---------------------------------------------------------------------------
// V [B,H,S,D] -> V^T [B,H,D,S]
// ---------------------------------------------------------------------------
__global__ __launch_bounds__(256) void transpose_v_kernel(
    const u16* __restrict__ vb, u16* __restrict__ vtb){
  __shared__ u16 tile[64][72];
  int bh = blockIdx.x >> 5;
  int st = blockIdx.x & 31;
  int t = threadIdx.x;
  const u16* src = vb + (size_t)bh*CS*CD + (size_t)st*64*CD;
  int r = t>>2, c = (t&3)*16;
  *(u16x8*)&tile[r][c]   = *(const u16x8*)(src + (size_t)r*CD + c);
  *(u16x8*)&tile[r][c+8] = *(const u16x8*)(src + (size_t)r*CD + c + 8);
  __syncthreads();
  int d = t>>2, s = (t&3)*16;
  u16x8 o0, o1;
  for (int j=0;j<8;j++){ o0[j] = tile[s+j][d]; o1[j] = tile[s+8+j][d]; }
  u16* dst = vtb + (size_t)bh*CD*CS + (size_t)d*CS + st*64 + s;
  *(u16x8*)dst = o0;
  *(u16x8*)(dst+8) = o1;
}

// ---------------------------------------------------------------------------
// GEMM1: qkv = xb @ wqkvT^T, m97-style global_load_lds staging, LN epilogue.
// ---------------------------------------------------------------------------
__global__ __launch_bounds__(256, 2) void gemm_qkv_ln_kernel(
    const u16* __restrict__ xb, const u16* __restrict__ wqkvT,
    const float* __restrict__ qsc, const float* __restrict__ qbi,
    const float* __restrict__ ksc, const float* __restrict__ kbi,
    u16* __restrict__ qb, u16* __restrict__ kb, u16* __restrict__ vb){
  __shared__ u16 al[128*64];
  __shared__ u16 bl[128*64];
  int t = threadIdx.x;
  int wv = t >> 6, lane = t & 63, lo = lane & 15, q4 = lane >> 4;
  int m0 = blockIdx.x * 128;
  int n0 = blockIdx.y * 128;
  int srow = lane >> 3, scol = (lane & 7) * 8;   // 8 rows x 64 cols per gload16
  const u16* ag = xb    + (size_t)(m0 + srow)*CC + scol;
  const u16* bg = wqkvT + (size_t)(n0 + srow)*CC + scol;

  f32x4 acc[2][8];
  for (int i=0;i<2;i++) for (int j=0;j<8;j++) acc[i][j] = (f32x4){0.f,0.f,0.f,0.f};

  for (int kk = 0; kk < 16; kk++){
    int k0 = kk * 64;
    for (int i = 0; i < 4; i++){
      int inst = i*4 + wv;
      gload16(ag + (size_t)inst*8*CC + k0, al + inst*512);
      gload16(bg + (size_t)inst*8*CC + k0, bl + inst*512);
    }
    __syncthreads();
    for (int ksI = 0; ksI < 2; ksI++){
      int koff = ksI*32 + q4*8;
      bf16x8 a0 = *(const bf16x8*)&al[(wv*32      + lo)*64 + koff];
      bf16x8 a1 = *(const bf16x8*)&al[(wv*32 + 16 + lo)*64 + koff];
      for (int nt=0; nt<8; nt++){
        bf16x8 b = *(const bf16x8*)&bl[(nt*16 + lo)*64 + koff];
        acc[0][nt] = mfma16(a0, b, acc[0][nt]);
        acc[1][nt] = mfma16(a1, b, acc[1][nt]);
      }
    }
    __syncthreads();
  }

  int three = n0 >> 10;
  int h0 = (n0 & 1023) >> 6;
  const float* scp = (three == 0) ? qsc : ksc;
  const float* bip = (three == 0) ? qbi : kbi;
  float outscale = (three == 0) ? 0.125f : 1.0f;   // fold 1/sqrt(D) into q
  u16* dst = (three == 0) ? qb : (three == 1 ? kb : vb);

  for (int rt = 0; rt < 2; rt++){
    int tg = m0 + wv*32 + rt*16 + q4*4;
    for (int hf = 0; hf < 2; hf++){
      int h = h0 + hf;
      for (int r = 0; r < 4; r++){
        int token = tg + r;
        int bb = token >> 11, ss = token & (CS-1);
        size_t base = (((size_t)(bb*CH + h))*CS + ss)*CD;
        if (three < 2){
          float s1 = 0.f, s2 = 0.f;
          for (int j=0;j<4;j++){ float v = acc[rt][hf*4+j][r]; s1 += v; s2 += v*v; }
          for (int off=8; off>=1; off>>=1){
            s1 += __shfl_xor(s1, off, 16);
            s2 += __shfl_xor(s2, off, 16);
          }
          float mean = s1 * (1.f/64.f);
          float var  = s2 * (1.f/64.f) - mean*mean;
          float rstd = rsqrtf(var + 1e-5f);
          for (int j=0;j<4;j++){
            int d = j*16 + lo;
            float v = (acc[rt][hf*4+j][r] - mean) * rstd * scp[d] + bip[d];
            dst[base + d] = f2bf(v * outscale);
          }
        } else {
          for (int j=0;j<4;j++){
            int d = j*16 + lo;
            dst[base + d] = f2bf(acc[rt][hf*4+j][r]);
          }
        }
      }
    }
  }
}

// ---------------------------------------------------------------------------
// Attention, LDS-staged: K and V^T tiles (64 sk x 64 d, 8 KB each) staged via
// global_load_lds, double-buffered. ONE barrier per tile, placed BEFORE the
// stage of tile t+1: the vmcnt(0) drain at the barrier only waits on loads
// that had the whole previous compute phase to land (m97-drain pre-covered).
// Cuts L1/L2 read traffic 4x vs per-wave global frag loads (round-6 finding:
// redundant loads saturated L2 delivery at ~50 B/cyc/CU).
// XOR swizzle: gload16 forces LDS phys layout (lane*16 contiguous), so the
// swizzle is applied on per-lane GLOBAL addresses: lane l of a chunk fetches
// logical 16B-slot (l&7)^(l>>3) of row l>>3. Frag reads then address
// phys slot = logical_slot ^ (row&7) -> all 8 bank groups hit, no 16-way
// conflicts. S^T = K.Q^T via 32x32x16 MFMA; no online max (|logit|<=8).
// ---------------------------------------------------------------------------
__global__ __launch_bounds__(256, 3) void attention_kernel(
    const u16* __restrict__ qb, const u16* __restrict__ kb,
    const u16* __restrict__ vtb, u16* __restrict__ attnb, float* __restrict__ ent){
  __shared__ __align__(16) u16 kl[2][64*64];    // [buf][sk][slot^] 8 KB each
  __shared__ __align__(16) u16 vl[2][64*64];    // [buf][d][slot^]  8 KB each
  __shared__ __align__(16) u16 pl[4][32][72];   // per-wave P, A-layout
  __shared__ __align__(16) float zl[4][32];
  int t = threadIdx.x;
  int wv = t >> 6, lane = t & 63;
  int col = lane & 31, hi = lane >> 5;
  // XCD swizzle: block n runs on XCD n%8; give each XCD 8 whole (b,h) heads.
  int n = blockIdx.x;
  int xc = n & 7, j = n >> 3;
  int bh = xc + 8*(j >> 4);
  int qt = j & 15;
  int bI = bh >> 4;
  int q0w = qt*128 + wv*32;
  const u16* qbp = qb  + (size_t)bh * CS * CD;
  const u16* kbp = kb  + (size_t)bh * CS * CD;
  const u16* vbp = vtb + (size_t)bh * CD * CS;

  // staging lane mapping: chunk = 8 rows; lane l covers row l>>3, logical
  // 16B-slot (l&7)^(l>>3) of that row (XOR swizzle via global address).
  int srow  = lane >> 3;
  int sslot = (lane & 7) ^ srow;

  // Q B-frags, held for the whole kernel
  bf16x8 qf[4];
  for (int ks=0;ks<4;ks++)
    qf[ks] = *(const bf16x8*)(qbp + (size_t)(q0w + col)*CD + ks*16 + hi*8);

  f32x16 o[2];
  for (int nt=0;nt<2;nt++) for (int i=0;i<16;i++) o[nt][i] = 0.f;
  float zacc = 0.f, tacc = 0.f;

  // prologue: stage tile 0 into buf 0 (each wave stages 2 K-chunks + 2 V-chunks)
  for (int c=0;c<2;c++){
    int chunk = wv*2 + c;                 // 0..7
    int row = chunk*8 + srow;
    gload16(kbp + (size_t)row*CD + sslot*8, &kl[0][chunk*512]);
    gload16(vbp + (size_t)row*CS + sslot*8, &vl[0][chunk*512]);
  }

  const int cshift = (col & 7);           // frag-read swizzle key

  for (int it = 0; it < 32; it++){
    const int cur = it & 1, nxt = cur ^ 1;
    __syncthreads();   // publishes buf cur; drain of cur's gloads pre-covered
    if (it < 31){
      int skn = (it+1)*64;
      for (int c=0;c<2;c++){
        int chunk = wv*2 + c;
        int row = chunk*8 + srow;
        gload16(kbp + (size_t)(skn + row)*CD + sslot*8, &kl[nxt][chunk*512]);
        gload16(vbp + (size_t)row*CS + skn + sslot*8, &vl[nxt][chunk*512]);
      }
    }

    // frag reads from LDS (XOR-swizzled addresses)
    bf16x8 kfr[2][4], vfr[2][4];
    for (int mt=0;mt<2;mt++)
      for (int ks=0;ks<4;ks++)
        kfr[mt][ks] = *(const bf16x8*)&kl[cur][(mt*32+col)*64 + (((2*ks+hi)^cshift)<<3)];
    for (int nt=0;nt<2;nt++)
      for (int ks=0;ks<4;ks++)
        vfr[nt][ks] = *(const bf16x8*)&vl[cur][(nt*32+col)*64 + (((2*ks+hi)^cshift)<<3)];

    // S^T = K . Q^T
    f32x16 sf[2];
    for (int mt=0;mt<2;mt++) for (int i=0;i<16;i++) sf[mt][i] = 0.f;
    for (int ks=0;ks<4;ks++){
      sf[0] = mfma32(kfr[0][ks], qf[ks], sf[0]);
      sf[1] = mfma32(kfr[1][ks], qf[ks], sf[1]);
    }

    // exp + Z/T partials + pack P (C row = (reg&3)+8*(reg>>2)+4*hi)
    for (int mt=0;mt<2;mt++){
      for (int g=0; g<4; g++){
        float l0 = sf[mt][g*4+0], l1 = sf[mt][g*4+1],
              l2 = sf[mt][g*4+2], l3 = sf[mt][g*4+3];
        float p0=__expf(l0), p1=__expf(l1), p2=__expf(l2), p3=__expf(l3);
        zacc += (p0+p1)+(p2+p3);
        tacc += (p0*l0+p1*l1)+(p2*l2+p3*l3);
        union { u16x4 v; unsigned u[2]; } pk;
        pk.u[0] = pack2bf(p0, p1);
        pk.u[1] = pack2bf(p2, p3);
        *(u16x4*)&pl[wv][col][mt*32 + g*8 + hi*4] = pk.v;
      }
    }

    // O += P . V (P re-read in A-layout from this wave's LDS region)
    for (int ks=0;ks<4;ks++){
      bf16x8 ap = *(const bf16x8*)&pl[wv][col][ks*16 + hi*8];
      o[0] = mfma32(ap, vfr[0][ks], o[0]);
      o[1] = mfma32(ap, vfr[1][ks], o[1]);
    }
  }

  // finalize: combine hi-halves of Z/T (lane col owns q-row col)
  float z2 = zacc + __shfl_xor(zacc, 32);
  float t2 = tacc + __shfl_xor(tacc, 32);
  float invz = 1.f / z2;
  if (hi == 0) zl[wv][col] = invz;

  // entropy: sum rows' (logZ - T/Z) over this wave, one atomic per wave
  float srowv = __logf(z2) - t2 * invz;
  float ev = (hi == 0) ? srowv : 0.f;
  for (int off=1; off<=32; off<<=1) ev += __shfl_xor(ev, off);
  if (lane == 0){
    float entscale = 1.0f / ((float)CH * (float)CS * logf((float)CS));
    atomicAdd(&ent[bI], ev * entscale);
  }

  // O write, head-major [B,H,S,D] (C: col=d-within-32, row=(reg&3)+8*(reg>>2)+4*hi)
  u16* obase = attnb + ((size_t)bh*CS + q0w)*CD;
  for (int nt=0;nt<2;nt++){
    for (int g=0;g<4;g++){
      f32x4 iz = *(const f32x4*)&zl[wv][g*8 + hi*4];
      for (int r=0;r<4;r++){
        int qrow = 8*g + 4*hi + r;
        obase[(size_t)qrow*CD + nt*32 + col] = f2bf(o[nt][g*4+r] * iz[r]);
      }
    }
  }
}

// ---------------------------------------------------------------------------
// GEMM3: out = attnH @ w_proj. attnH is head-major [B,H,S,D]; K-tile kk is
// exactly head kk, so A-loads are fully contiguous (1 KB per gload16).
// ---------------------------------------------------------------------------
__global__ __launch_bounds__(256, 2) void gemm_out_kernel(
    const u16* __restrict__ attnH, const u16* __restrict__ wprojT,
    float* __restrict__ out){
  __shared__ u16 al[128*64];
  __shared__ u16 bl[128*64];
  int t = threadIdx.x;
  int wv = t >> 6, lane = t & 63, lo = lane & 15, q4 = lane >> 4;
  int m0 = blockIdx.x * 128;
  int n0 = blockIdx.y * 128;
  int b  = m0 >> 11, s0 = m0 & (CS-1);
  int srow = lane >> 3, scol = (lane & 7) * 8;
  const u16* bg = wprojT + (size_t)(n0 + srow)*CC + scol;

  f32x4 acc[2][8];
  for (int i=0;i<2;i++) for (int j=0;j<8;j++) acc[i][j] = (f32x4){0.f,0.f,0.f,0.f};

  for (int kk = 0; kk < 16; kk++){
    const u16* abase = attnH + ((size_t)(b*CH + kk)*CS + s0 + srow)*CD + scol;
    for (int i = 0; i < 4; i++){
      int inst = i*4 + wv;
      gload16(abase + (size_t)inst*8*CD, al + inst*512);
      gload16(bg + (size_t)inst*8*CC + kk*64, bl + inst*512);
    }
    __syncthreads();
    for (int ksI = 0; ksI < 2; ksI++){
      int koff = ksI*32 + q4*8;
      bf16x8 a0 = *(const bf16x8*)&al[(wv*32      + lo)*64 + koff];
      bf16x8 a1 = *(const bf16x8*)&al[(wv*32 + 16 + lo)*64 + koff];
      for (int nt=0; nt<8; nt++){
        bf16x8 b2 = *(const bf16x8*)&bl[(nt*16 + lo)*64 + koff];
        acc[0][nt] = mfma16(a0, b2, acc[0][nt]);
        acc[1][nt] = mfma16(a1, b2, acc[1][nt]);
      }
    }
    __syncthreads();
  }

  for (int rt=0;rt<2;rt++){
    for (int r=0;r<4;r++){
      int row = m0 + wv*32 + rt*16 + q4*4 + r;
      for (int nt=0;nt<8;nt++)
        out[(size_t)row*CC + n0 + nt*16 + lo] = acc[rt][nt][r];
    }
  }
}

// ---------------------------------------------------------------------------
extern "C" void kernel_launch(void* const* d_in, const int* in_sizes, int n_in,
                              void* d_out, int out_size, void* d_ws, size_t ws_size,
                              hipStream_t stream) {
  const float* x      = (const float*)d_in[0];
  const float* w_qkv  = (const float*)d_in[1];
  const float* w_proj = (const float*)d_in[2];
  const float* q_scale= (const float*)d_in[3];
  const float* q_bias = (const float*)d_in[4];
  const float* k_scale= (const float*)d_in[5];
  const float* k_bias = (const float*)d_in[6];
  float* out = (float*)d_out;
  float* ent = out + (size_t)CBS * CC;

  // workspace: 75.5 MB total, with lifetime-based aliasing:
  //   xb slot reused as vbT; vb slot reused as attn (both [B,H,S,D]).
  u16* xb     = (u16*)d_ws;                       // [8192][1024]  (later: vbT [B,H,D,S])
  u16* wqkvT  = xb     + (size_t)CBS*CC;          // [3072][1024]
  u16* wprojT = wqkvT  + (size_t)3*CC*CC;         // [1024][1024]
  u16* qb     = wprojT + (size_t)CC*CC;           // [B,H,S,D]
  u16* kb     = qb + (size_t)CB*CH*CS*CD;
  u16* vb     = kb + (size_t)CB*CH*CS*CD;         // (later: attnH [B,H,S,D])
  u16* vbT    = xb;
  u16* attn   = vb;

  convert_x_kernel<<<dim3(CBS*CC/(256*8)), 256, 0, stream>>>(x, xb, ent);
  transpose_convert_kernel<CC, 3*CC><<<dim3((CC/64)*(3*CC/64)), 256, 0, stream>>>(w_qkv, wqkvT);
  transpose_convert_kernel<CC, CC><<<dim3((CC/64)*(CC/64)), 256, 0, stream>>>(w_proj, wprojT);
  gemm_qkv_ln_kernel<<<dim3(CBS/128, 3*CC/128), 256, 0, stream>>>(
      xb, wqkvT, q_scale, q_bias, k_scale, k_bias, qb, kb, vb);
  transpose_v_kernel<<<dim3(CB*CH*(CS/64)), 256, 0, stream>>>(vb, vbT);
  attention_kernel<<<dim3(CB*CH*(CS/128)), 256, 0, stream>>>(qb, kb, vbT, attn, ent);
  gemm_out_kernel<<<dim3(CBS/128, CC/128), 256, 0, stream>>>(attn, wprojT, out);
}